// Round 3
// baseline (325.776 us; speedup 1.0000x reference)
//
#include <hip/hip_runtime.h>

typedef unsigned short u16;
typedef unsigned int   u32;
typedef u16  u16x2 __attribute__((ext_vector_type(2)));
typedef u16  u16x4 __attribute__((ext_vector_type(4)));
typedef u16  u16x8 __attribute__((ext_vector_type(8)));
typedef short s8v  __attribute__((ext_vector_type(8)));   // 8 bf16, MFMA A/B frag (K=32 shapes)
typedef float f4v  __attribute__((ext_vector_type(4)));   // MFMA C/D frag
typedef u32  u32x2 __attribute__((ext_vector_type(2)));
typedef u32  u32x4 __attribute__((ext_vector_type(4)));

#define L_SEQ 2048
#define B_SZ  4
#define E_DIM 512
#define H_CNT 8
#define HD    64
#define HID   2048
#define M_ROWS (L_SEQ * B_SZ)   // 8192
#define QSCALE 0.18033688011112042f   // 0.125 * log2(e)

__device__ __forceinline__ u16 f2b(float f) {
    unsigned u = __builtin_bit_cast(unsigned, f);
    u += 0x7fffu + ((u >> 16) & 1u);               // RNE
    return (u16)(u >> 16);
}
__device__ __forceinline__ float b2f(u16 u) {
    u32 x = ((u32)u) << 16; return __builtin_bit_cast(float, x);
}
#if defined(__has_builtin)
#if __has_builtin(__builtin_amdgcn_cvt_pk_bf16_f32)
#define HAVE_PK_BF16 1
#endif
#if __has_builtin(__builtin_amdgcn_rcpf)
#define HAVE_RCPF 1
#endif
#endif
__device__ __forceinline__ u32 pk_trunc(float a, float b) {
#ifdef HAVE_PK_BF16
    typedef __bf16 bf2 __attribute__((ext_vector_type(2)));
    bf2 r = __builtin_amdgcn_cvt_pk_bf16_f32(a, b);
    return __builtin_bit_cast(u32, r);
#else
    u32 ua = __builtin_bit_cast(u32, a), ub = __builtin_bit_cast(u32, b);
    return (ua >> 16) | (ub & 0xffff0000u);
#endif
}
__device__ __forceinline__ float frcp(float x) {
#ifdef HAVE_RCPF
    return __builtin_amdgcn_rcpf(x);
#else
    return 1.0f / x;
#endif
}
__device__ __forceinline__ void gload_lds16(const u16* g, u16* l) {
    __builtin_amdgcn_global_load_lds((__attribute__((address_space(1))) void*)(u16*)g,
                                     (__attribute__((address_space(3))) void*)l, 16, 0, 0);
}
// tanh-GELU in sigmoid form (|err| < 1e-3, below bf16 rounding of the result)
__device__ __forceinline__ float gelu_f(float v) {
    float y2 = v * (1.5957691216f + 0.0713548576f * v * v);
    return v / (1.0f + __expf(-y2));
}

// ---------------------------------------------------------------- PE table (b,e) -> 2048 floats
__global__ __launch_bounds__(256) void pe_tab_k(float* __restrict__ pet) {
    int i = blockIdx.x * 256 + threadIdx.x;          // 2048
    int e = i & (E_DIM - 1);
    float t = (float)(i >> 9) + 1.0f;
    int ee = (e & 1) ? (e + 1) : e;
    float w = exp2f((-(float)ee / 512.0f) * 13.287712379549449f);
    pet[i] = (e & 1) ? cosf(t * w) : sinf(t * w);
}

__global__ __launch_bounds__(256) void pe_add_k(const float* __restrict__ x,
                                                const float* __restrict__ pet,
                                                u16* __restrict__ xpb) {
    int idx = (blockIdx.x * 256 + threadIdx.x) * 4;
    f4v v = *(const f4v*)(x + idx);
    f4v p = *(const f4v*)(pet + (idx & 2047));
    u16x4 o;
#pragma unroll
    for (int i = 0; i < 4; ++i) o[i] = f2b(v[i] + p[i]);
    *(u16x4*)(xpb + idx) = o;
}

__global__ __launch_bounds__(256) void conv4_k(const float* __restrict__ s1, u16* __restrict__ d1, int n1,
                                               const float* __restrict__ s2, u16* __restrict__ d2, int n2,
                                               const float* __restrict__ s3, u16* __restrict__ d3, int n3,
                                               const float* __restrict__ s4, u16* __restrict__ d4) {
    int o = (blockIdx.x * 256 + threadIdx.x) * 4;
    const float* s; u16* d;
    if (o < n1) { s = s1; d = d1; }
    else { o -= n1;
        if (o < n2) { s = s2; d = d2; }
        else { o -= n2;
            if (o < n3) { s = s3; d = d3; }
            else { o -= n3; s = s4; d = d4; } } }
    f4v v = *(const f4v*)(s + o);
    u16x4 q;
#pragma unroll
    for (int i = 0; i < 4; ++i) q[i] = f2b(v[i]);
    *(u16x4*)(d + o) = q;
}

// ---------------------------------------------------------------- LN combine (wave per row)
template <int NP, bool WRITEF, bool WRITEB>
__global__ __launch_bounds__(256)
void ln_c(const u16* __restrict__ p0, const u16* __restrict__ p1,
          const u16* __restrict__ p2, const u16* __restrict__ p3,
          const float* __restrict__ bias, const u16* __restrict__ resid,
          const float* __restrict__ gw, const float* __restrict__ bw,
          float* __restrict__ outF, u16* __restrict__ outB) {
    int wave = threadIdx.x >> 6, lane = threadIdx.x & 63;
    size_t row = (size_t)blockIdx.x * 4 + wave;
    size_t off = row * E_DIM + lane * 8;
    u16x8 rv = *(const u16x8*)(resid + off);
    f4v a, b;
#pragma unroll
    for (int i = 0; i < 4; ++i) { a[i] = b2f(rv[i]); b[i] = b2f(rv[i + 4]); }
    a += *(const f4v*)(bias + lane * 8);
    b += *(const f4v*)(bias + lane * 8 + 4);
    const u16* ps[4] = {p0, p1, p2, p3};
#pragma unroll
    for (int z = 0; z < NP; ++z) {
        u16x8 t = *(const u16x8*)(ps[z] + off);
#pragma unroll
        for (int i = 0; i < 4; ++i) { a[i] += b2f(t[i]); b[i] += b2f(t[i + 4]); }
    }
    float s = (a[0] + a[1]) + (a[2] + a[3]) + (b[0] + b[1]) + (b[2] + b[3]);
#pragma unroll
    for (int o = 1; o < 64; o <<= 1) s += __shfl_xor(s, o, 64);
    float mu = s * (1.0f / E_DIM);
    float q = 0.f;
#pragma unroll
    for (int i = 0; i < 4; ++i) { float d = a[i] - mu; q += d * d; }
#pragma unroll
    for (int i = 0; i < 4; ++i) { float d = b[i] - mu; q += d * d; }
#pragma unroll
    for (int o = 1; o < 64; o <<= 1) q += __shfl_xor(q, o, 64);
    float rstd = rsqrtf(q * (1.0f / E_DIM) + 1e-5f);
    f4v g0 = *(const f4v*)(gw + lane * 8), g1 = *(const f4v*)(gw + lane * 8 + 4);
    f4v w0 = *(const f4v*)(bw + lane * 8), w1 = *(const f4v*)(bw + lane * 8 + 4);
    f4v y0, y1;
#pragma unroll
    for (int i = 0; i < 4; ++i) { y0[i] = (a[i] - mu) * rstd * g0[i] + w0[i];
                                  y1[i] = (b[i] - mu) * rstd * g1[i] + w1[i]; }
    if (WRITEF) {
        *(f4v*)(outF + off)     = y0;
        *(f4v*)(outF + off + 4) = y1;
    }
    if (WRITEB) {
        u16x8 o;
#pragma unroll
        for (int i = 0; i < 4; ++i) { o[i] = f2b(y0[i]); o[i + 4] = f2b(y1[i]); }
        *(u16x8*)(outB + off) = o;
    }
}

// ---------------------------------------------------------------- V transpose [b][h][l][d] -> [b][h][d][l]
__global__ __launch_bounds__(256) void transpose_v_k(const u16* __restrict__ vb,
                                                     u16* __restrict__ vt) {
    __shared__ __align__(16) u16 T[64 * 66];
    int t = threadIdx.x;
    int lt = blockIdx.x, bh = blockIdx.y;
    const u16* src = vb + (size_t)bh * (L_SEQ * HD) + (size_t)lt * 64 * HD;
    int lr = t >> 2, d0 = (t & 3) * 16;
    s8v va = *(const s8v*)(src + lr * HD + d0);
    s8v vb8 = *(const s8v*)(src + lr * HD + d0 + 8);
#pragma unroll
    for (int c = 0; c < 4; ++c) {
        u16x2 p0; p0[0] = (u16)va[c * 2]; p0[1] = (u16)va[c * 2 + 1];
        u16x2 p1; p1[0] = (u16)vb8[c * 2]; p1[1] = (u16)vb8[c * 2 + 1];
        *(u16x2*)(&T[lr * 66 + d0 + c * 2])     = p0;
        *(u16x2*)(&T[lr * 66 + d0 + 8 + c * 2]) = p1;
    }
    __syncthreads();
    int d = t >> 2, l0 = (t & 3) * 16;
    u16 tmp[16];
#pragma unroll
    for (int i = 0; i < 16; ++i) tmp[i] = T[(l0 + i) * 66 + d];
    u16* dst = vt + (size_t)bh * (L_SEQ * HD) + (size_t)d * L_SEQ + lt * 64 + l0;
    u16x8 o0, o1;
#pragma unroll
    for (int i = 0; i < 8; ++i) { o0[i] = tmp[i]; o1[i] = tmp[8 + i]; }
    *(u16x8*)dst       = o0;
    *(u16x8*)(dst + 8) = o1;
}

// ---------------------------------------------------------------- GEMM 128x128 BK32 dbuf + XCD swizzle (R14-proven)
// runtime K loop (compiler handles it better than full unroll — R15 lesson).
// NT = n-tiles. MODE 0: QKV scatter (Q pre-scaled); MODE 2: tanh-GELU bf16.
template <int MODE, int NT>
__global__ __launch_bounds__(256, 4)
void gemm_bt(const u16* __restrict__ A, const u16* __restrict__ Bw,
             const float* __restrict__ bias, int M, int N, int K,
             u16* __restrict__ outB,
             u16* __restrict__ oq, u16* __restrict__ okk, u16* __restrict__ ov) {
    __shared__ __align__(16) u16 As[2][128 * 32];
    __shared__ __align__(16) u16 Bs[2][128 * 32];
    const int tid = threadIdx.x;
    const int wave = tid >> 6, lane = tid & 63;
    const int col = lane & 15, quad = lane >> 4;
    const int n = blockIdx.x;
    const int xcd = n & 7, loc = n >> 3;
    const int mpx = (M / 128) >> 3;
    const int bm = (xcd * mpx + loc / NT) * 128;
    const int bn = (loc % NT) * 128;
    const int wm = (wave >> 1) * 64, wn = (wave & 1) * 64;
    f4v acc[4][4] = {};
    const int srow = wave * 16 + (lane >> 2);
    const int soff = (lane & 3) * 8;
    const u16* Ag = A + (size_t)(bm + srow) * K + soff;
    const u16* Bg = Bw + (size_t)(bn + srow) * K + soff;
    const int wo = wave * 512;
    gload_lds16(Ag,                  &As[0][wo]);
    gload_lds16(Ag + (size_t)64 * K, &As[0][wo + 2048]);
    gload_lds16(Bg,                  &Bs[0][wo]);
    gload_lds16(Bg + (size_t)64 * K, &Bs[0][wo + 2048]);
    const int nit = K >> 5;
    for (int t = 0; t < nit; ++t) {
        const int cur = t & 1, nxt = cur ^ 1;
        __syncthreads();
        if (t + 1 < nit) {
            const int kc = (t + 1) * 32;
            gload_lds16(Ag + kc,                  &As[nxt][wo]);
            gload_lds16(Ag + (size_t)64 * K + kc, &As[nxt][wo + 2048]);
            gload_lds16(Bg + kc,                  &Bs[nxt][wo]);
            gload_lds16(Bg + (size_t)64 * K + kc, &Bs[nxt][wo + 2048]);
        }
        s8v af[4], bf[4];
#pragma unroll
        for (int i = 0; i < 4; ++i) af[i] = *(const s8v*)(&As[cur][(wm + i * 16 + col) * 32 + quad * 8]);
#pragma unroll
        for (int j = 0; j < 4; ++j) bf[j] = *(const s8v*)(&Bs[cur][(wn + j * 16 + col) * 32 + quad * 8]);
#pragma unroll
        for (int i = 0; i < 4; ++i)
#pragma unroll
            for (int j = 0; j < 4; ++j)
                acc[i][j] = __builtin_amdgcn_mfma_f32_16x16x32_bf16(af[i], bf[j], acc[i][j], 0, 0, 0);
    }
#pragma unroll
    for (int j = 0; j < 4; ++j) {
        int gn = bn + wn + j * 16 + col;
        float bv = bias[gn];
        int which = gn >> 9, hh = (gn >> 6) & 7, d = gn & 63;
        u16* dst = (MODE == 0) ? ((which == 0) ? oq : ((which == 1) ? okk : ov)) : outB;
        float qs = (MODE == 0 && which == 0) ? QSCALE : 1.0f;
#pragma unroll
        for (int i = 0; i < 4; ++i) {
            int gm0 = bm + wm + i * 16 + quad * 4;
#pragma unroll
            for (int r = 0; r < 4; ++r) {
                float v = acc[i][j][r] + bv;
                int m = gm0 + r;
                if (MODE == 2) {
                    outB[(size_t)m * N + gn] = f2b(gelu_f(v));
                } else {
                    int l = m >> 2, bb = m & 3;
                    dst[((size_t)(bb * H_CNT + hh) * L_SEQ + l) * HD + d] = f2b(v * qs);
                }
            }
        }
    }
}

// ---------------------------------------------------------------- K-split partial GEMM BK32 dbuf + XCD swizzle (R14)
__global__ __launch_bounds__(256, 4)
void gemm_ks(const u16* __restrict__ A, const u16* __restrict__ Bw,
             int N, int K, int Kper,
             u16* __restrict__ q0, u16* __restrict__ q1) {
    __shared__ __align__(16) u16 As[2][128 * 32];
    __shared__ __align__(16) u16 Bs[2][128 * 32];
    const int tid = threadIdx.x;
    const int wave = tid >> 6, lane = tid & 63;
    const int col = lane & 15, quad = lane >> 4;
    const int n = blockIdx.x;
    const int xcd = n & 7, loc = n >> 3;             // loc in [0,64)
    const int bn = (loc & 3) * 128;
    const int bm = (xcd * 8 + ((loc >> 2) & 7)) * 128;
    const int kz = loc >> 5;
    u16* pz = kz ? q1 : q0;
    const int wm = (wave >> 1) * 64, wn = (wave & 1) * 64;
    f4v acc[4][4] = {};
    const int srow = wave * 16 + (lane >> 2);
    const int soff = (lane & 3) * 8;
    const u16* Ag = A + (size_t)(bm + srow) * K + kz * Kper + soff;
    const u16* Bg = Bw + (size_t)(bn + srow) * K + kz * Kper + soff;
    const int wo = wave * 512;
    gload_lds16(Ag,                  &As[0][wo]);
    gload_lds16(Ag + (size_t)64 * K, &As[0][wo + 2048]);
    gload_lds16(Bg,                  &Bs[0][wo]);
    gload_lds16(Bg + (size_t)64 * K, &Bs[0][wo + 2048]);
    const int nit = Kper >> 5;
    for (int t = 0; t < nit; ++t) {
        const int cur = t & 1, nxt = cur ^ 1;
        __syncthreads();
        if (t + 1 < nit) {
            const int kc = (t + 1) * 32;
            gload_lds16(Ag + kc,                  &As[nxt][wo]);
            gload_lds16(Ag + (size_t)64 * K + kc, &As[nxt][wo + 2048]);
            gload_lds16(Bg + kc,                  &Bs[nxt][wo]);
            gload_lds16(Bg + (size_t)64 * K + kc, &Bs[nxt][wo + 2048]);
        }
        s8v af[4], bf[4];
#pragma unroll
        for (int i = 0; i < 4; ++i) af[i] = *(const s8v*)(&As[cur][(wm + i * 16 + col) * 32 + quad * 8]);
#pragma unroll
        for (int j = 0; j < 4; ++j) bf[j] = *(const s8v*)(&Bs[cur][(wn + j * 16 + col) * 32 + quad * 8]);
#pragma unroll
        for (int i = 0; i < 4; ++i)
#pragma unroll
            for (int j = 0; j < 4; ++j)
                acc[i][j] = __builtin_amdgcn_mfma_f32_16x16x32_bf16(af[i], bf[j], acc[i][j], 0, 0, 0);
    }
#pragma unroll
    for (int j = 0; j < 4; ++j) {
        int gn = bn + wn + j * 16 + col;
#pragma unroll
        for (int i = 0; i < 4; ++i) {
            int m0 = bm + wm + i * 16 + quad * 4;
#pragma unroll
            for (int r = 0; r < 4; ++r)
                pz[(size_t)(m0 + r) * N + gn] = f2b(acc[i][j][r]);
        }
    }
}

// ---------------------------------------------------------------- flash attention v9: LDS-free, direct-from-L2
// K/V per XCD = 2MB (L2-resident via XCD-chunked bh mapping). Fragments are loaded straight from
// global into MFMA registers at the exact addresses the old LDS path resolved to (swizzles cancel;
// sigma folded into the per-lane K row pointer). No barriers, register double-buffer for K,
// V issued chunk-top (QK+exp covers L2 latency). l-sum on VALU (off the MFMA pipe).
__global__ __launch_bounds__(256, 2)
void attn_k(const u16* __restrict__ qg, const u16* __restrict__ kg,
            const u16* __restrict__ vtg, u16* __restrict__ og) {
    const int tid = threadIdx.x;
    const int wave = tid >> 6, lane = tid & 63;
    const int col = lane & 15, quad = lane >> 4;
    const int flat = blockIdx.x;
    const int xcd = flat & 7, loc = flat >> 3;       // loc in [0,64)
    const int bh = xcd * 4 + (loc >> 4);             // 4 heads per XCD
    const int qc = loc & 15;
    const size_t base = (size_t)bh * (L_SEQ * HD);
    s8v qf[2][2];
#pragma unroll
    for (int t = 0; t < 2; ++t) {
        const int qrow = qc * 128 + wave * 32 + t * 16 + col;
#pragma unroll
        for (int hh = 0; hh < 2; ++hh)
            qf[t][hh] = *(const s8v*)(qg + base + (size_t)qrow * HD + hh * 32 + quad * 8);
    }
    f4v oa[2][4] = {};
    float ls0 = 0.f, ls1 = 0.f;
    // sigma row permutation folded into K pointers: A-row (j,col) holds kv = sigma
    const u16* kr[4];
#pragma unroll
    for (int j = 0; j < 4; ++j) {
        int sig = 32 * (j >> 1) + 8 * (col >> 2) + 4 * (j & 1) + (col & 3);
        kr[j] = kg + base + (size_t)sig * HD + quad * 8;
    }
    // V^T fragment pointers: row = d (dj*16+col), k-offset c2*32 + quad*8
    const u16* vr[2][4];
#pragma unroll
    for (int c2 = 0; c2 < 2; ++c2)
#pragma unroll
        for (int dj = 0; dj < 4; ++dj)
            vr[c2][dj] = vtg + base + (size_t)(dj * 16 + col) * L_SEQ + c2 * 32 + quad * 8;

    s8v kfA[4][2], kfB[4][2];
#pragma unroll
    for (int j = 0; j < 4; ++j) {
        kfA[j][0] = *(const s8v*)(kr[j]);
        kfA[j][1] = *(const s8v*)(kr[j] + 32);
    }

#define ATTN_STEP(KF_CUR, KF_NXT, KOFF, VOFF)                                              \
    {                                                                                      \
        s8v vf0[4], vf1[4];                                                                \
        _Pragma("unroll")                                                                  \
        for (int dj = 0; dj < 4; ++dj) {                                                   \
            vf0[dj] = *(const s8v*)(vr[0][dj] + (VOFF));                                   \
            vf1[dj] = *(const s8v*)(vr[1][dj] + (VOFF));                                   \
        }                                                                                  \
        _Pragma("unroll")                                                                  \
        for (int j = 0; j < 4; ++j) {                                                      \
            KF_NXT[j][0] = *(const s8v*)(kr[j] + (KOFF));                                  \
            KF_NXT[j][1] = *(const s8v*)(kr[j] + (KOFF) + 32);                             \
        }                                                                                  \
        f4v st[2][4];                                                                      \
        _Pragma("unroll")                                                                  \
        for (int j = 0; j < 4; ++j) {                                                      \
            _Pragma("unroll")                                                              \
            for (int t = 0; t < 2; ++t) {                                                  \
                f4v z = {};                                                                \
                z = __builtin_amdgcn_mfma_f32_16x16x32_bf16(KF_CUR[j][0], qf[t][0], z, 0, 0, 0); \
                z = __builtin_amdgcn_mfma_f32_16x16x32_bf16(KF_CUR[j][1], qf[t][1], z, 0, 0, 0); \
                st[t][j] = z;                                                              \
            }                                                                              \
        }                                                                                  \
        u32 pk[2][4][2];                                                                   \
        _Pragma("unroll")                                                                  \
        for (int t = 0; t < 2; ++t)                                                        \
            _Pragma("unroll")                                                              \
            for (int j = 0; j < 4; ++j) {                                                  \
                f4v p;                                                                     \
                _Pragma("unroll")                                                          \
                for (int r = 0; r < 4; ++r) p[r] = __builtin_amdgcn_exp2f(st[t][j][r]);    \
                float psum = (p[0] + p[1]) + (p[2] + p[3]);                                \
                if (t == 0) ls0 += psum; else ls1 += psum;                                 \
                pk[t][j][0] = pk_trunc(p[0], p[1]);                                        \
                pk[t][j][1] = pk_trunc(p[2], p[3]);                                        \
            }                                                                              \
        _Pragma("unroll")                                                                  \
        for (int c2 = 0; c2 < 2; ++c2) {                                                   \
            s8v pf[2];                                                                     \
            _Pragma("unroll")                                                              \
            for (int t = 0; t < 2; ++t) {                                                  \
                u32x4 q4 = {pk[t][2 * c2][0], pk[t][2 * c2][1],                            \
                            pk[t][2 * c2 + 1][0], pk[t][2 * c2 + 1][1]};                   \
                pf[t] = __builtin_bit_cast(s8v, q4);                                       \
            }                                                                              \
            _Pragma("unroll")                                                              \
            for (int dj = 0; dj < 4; ++dj) {                                               \
                s8v vf = (c2 == 0) ? vf0[dj] : vf1[dj];                                    \
                _Pragma("unroll")                                                          \
                for (int t = 0; t < 2; ++t)                                                \
                    oa[t][dj] = __builtin_amdgcn_mfma_f32_16x16x32_bf16(pf[t], vf, oa[t][dj], 0, 0, 0); \
            }                                                                              \
        }                                                                                  \
    }

    for (int it = 0; it < 32; it += 2) {
        const size_t ko1 = (size_t)(it + 1) * (64 * HD);                    // it+1 <= 31
        const size_t ko2 = (size_t)((it + 2) < 32 ? (it + 2) : 0) * (64 * HD);
        const size_t vo1 = (size_t)it * 64, vo2 = (size_t)(it + 1) * 64;
        ATTN_STEP(kfA, kfB, ko1, vo1);
        ATTN_STEP(kfB, kfA, ko2, vo2);
    }
#undef ATTN_STEP

    // complete l over quads (lanes sharing col), then normalize + write final O
    ls0 += __shfl_xor(ls0, 16, 64); ls0 += __shfl_xor(ls0, 32, 64);
    ls1 += __shfl_xor(ls1, 16, 64); ls1 += __shfl_xor(ls1, 32, 64);
    const int b = bh >> 3, hd = bh & 7;
#pragma unroll
    for (int t = 0; t < 2; ++t)
#pragma unroll
        for (int r = 0; r < 4; ++r) {
            float lv = __shfl(t == 0 ? ls0 : ls1, quad * 4 + r, 64);
            float inv = frcp(lv);
            int lrow = qc * 128 + wave * 32 + t * 16 + quad * 4 + r;
            size_t mrow = (size_t)(lrow * 4 + b) * E_DIM + hd * HD;
#pragma unroll
            for (int dj = 0; dj < 4; ++dj)
                og[mrow + dj * 16 + col] = f2b(oa[t][dj][r] * inv);
        }
}

// ---------------------------------------------------------------- host
extern "C" void kernel_launch(void* const* d_in, const int* in_sizes, int n_in,
                              void* d_out, int out_size, void* d_ws, size_t ws_size,
                              hipStream_t stream) {
    const float* x     = (const float*)d_in[0];
    const float* w_qkv = (const float*)d_in[1];
    const float* b_qkv = (const float*)d_in[2];
    const float* w_out = (const float*)d_in[3];
    const float* b_out = (const float*)d_in[4];
    const float* w1    = (const float*)d_in[5];
    const float* b1    = (const float*)d_in[6];
    const float* w2    = (const float*)d_in[7];
    const float* b2    = (const float*)d_in[8];
    const float* ln_g  = (const float*)d_in[9];
    const float* ln_b  = (const float*)d_in[10];

    char* ws = (char*)d_ws;
    u16*   WQKV = (u16*)(ws + 0);                    // 1.5 MB
    u16*   WOUT = (u16*)(ws + 1572864);              // 0.5 MB
    u16*   W1B  = (u16*)(ws + 2097152);              // 2 MB
    u16*   W2B  = (u16*)(ws + 4194304);              // 2 MB
    u16*   XPB  = (u16*)(ws + 6291456);              // 8 MB  x+pe bf16 (resid 1)
    u16*   QB   = (u16*)(ws + 14680064);             // 8 MB
    u16*   KB   = (u16*)(ws + 23068672);             // 8 MB
    u16*   VB   = (u16*)(ws + 31457280);             // 8 MB
    u16*   VT   = (u16*)(ws + 39845888);             // 8 MB
    float* PET  = (float*)(ws + 82837504);           // 8 KB PE table
    // aliases (disjoint lifetimes):
    u16*   OB   = VB;                                // attn out (VB free after transpose)
    u16*   OP0  = (u16*)(ws + 48234496);             // out-proj partials
    u16*   OP1  = (u16*)(ws + 56623104);
    u16*   X3B  = QB;                                // LN1 out bf16 (QB free after attn; resid 2)
    u16*   HB   = (u16*)(ws + 48234496);             // FFN1 out 32MB (over OPx, free after ln_c)
    u16*   FP0  = XPB;                               // FFN2 partials (free by FFN2)
    u16*   FP1  = KB;

    pe_tab_k<<<8, 256, 0, stream>>>(PET);
    pe_add_k<<<4096, 256, 0, stream>>>(x, PET, XPB);
    conv4_k<<<3072, 256, 0, stream>>>(w_qkv, WQKV, 3 * E_DIM * E_DIM,
                                      w_out, WOUT, E_DIM * E_DIM,
                                      w1, W1B, HID * E_DIM,
                                      w2, W2B);
    gemm_bt<0, 12><<<768, 256, 0, stream>>>(XPB, WQKV, b_qkv, M_ROWS, 3 * E_DIM, E_DIM,
                                            nullptr, QB, KB, VB);
    transpose_v_k<<<dim3(32, 32), 256, 0, stream>>>(VB, VT);
    attn_k<<<512, 256, 0, stream>>>(QB, KB, VT, OB);
    gemm_ks<<<512, 256, 0, stream>>>(OB, WOUT, E_DIM, E_DIM, 256, OP0, OP1);
    ln_c<2, false, true><<<2048, 256, 0, stream>>>(OP0, OP1, nullptr, nullptr,
                                                   b_out, XPB, ln_g, ln_b, nullptr, X3B);
    gemm_bt<2, 16><<<1024, 256, 0, stream>>>(X3B, W1B, b1, M_ROWS, HID, E_DIM,
                                             HB, nullptr, nullptr, nullptr);
    gemm_ks<<<512, 256, 0, stream>>>(HB, W2B, E_DIM, HID, 1024, FP0, FP1);
    ln_c<2, true, false><<<2048, 256, 0, stream>>>(FP0, FP1, nullptr, nullptr,
                                                   b2, X3B, ln_g, ln_b, (float*)d_out, nullptr);
}

// Round 5
// 251.802 us; speedup vs baseline: 1.2938x; 1.2938x over previous
//
#include <hip/hip_runtime.h>

typedef unsigned short u16;
typedef unsigned int   u32;
typedef u16  u16x2 __attribute__((ext_vector_type(2)));
typedef u16  u16x4 __attribute__((ext_vector_type(4)));
typedef u16  u16x8 __attribute__((ext_vector_type(8)));
typedef short s8v  __attribute__((ext_vector_type(8)));   // 8 bf16, MFMA A/B frag (K=32 shapes)
typedef float f4v  __attribute__((ext_vector_type(4)));   // MFMA C/D frag
typedef u32  u32x2 __attribute__((ext_vector_type(2)));
typedef u32  u32x4 __attribute__((ext_vector_type(4)));

#define L_SEQ 2048
#define B_SZ  4
#define E_DIM 512
#define H_CNT 8
#define HD    64
#define HID   2048
#define M_ROWS (L_SEQ * B_SZ)   // 8192
#define QSCALE 0.18033688011112042f   // 0.125 * log2(e)

__device__ __forceinline__ u16 f2b(float f) {
    unsigned u = __builtin_bit_cast(unsigned, f);
    u += 0x7fffu + ((u >> 16) & 1u);               // RNE
    return (u16)(u >> 16);
}
__device__ __forceinline__ float b2f(u16 u) {
    u32 x = ((u32)u) << 16; return __builtin_bit_cast(float, x);
}
#if defined(__has_builtin)
#if __has_builtin(__builtin_amdgcn_cvt_pk_bf16_f32)
#define HAVE_PK_BF16 1
#endif
#if __has_builtin(__builtin_amdgcn_rcpf)
#define HAVE_RCPF 1
#endif
#endif
__device__ __forceinline__ u32 pk_trunc(float a, float b) {
#ifdef HAVE_PK_BF16
    typedef __bf16 bf2 __attribute__((ext_vector_type(2)));
    bf2 r = __builtin_amdgcn_cvt_pk_bf16_f32(a, b);
    return __builtin_bit_cast(u32, r);
#else
    u32 ua = __builtin_bit_cast(u32, a), ub = __builtin_bit_cast(u32, b);
    return (ua >> 16) | (ub & 0xffff0000u);
#endif
}
__device__ __forceinline__ float frcp(float x) {
#ifdef HAVE_RCPF
    return __builtin_amdgcn_rcpf(x);
#else
    return 1.0f / x;
#endif
}
__device__ __forceinline__ void gload_lds16(const u16* g, u16* l) {
    __builtin_amdgcn_global_load_lds((__attribute__((address_space(1))) void*)(u16*)g,
                                     (__attribute__((address_space(3))) void*)l, 16, 0, 0);
}
// tanh-GELU in sigmoid form (|err| < 1e-3, below bf16 rounding of the result)
__device__ __forceinline__ float gelu_f(float v) {
    float y2 = v * (1.5957691216f + 0.0713548576f * v * v);
    return v / (1.0f + __expf(-y2));
}

// ---------------------------------------------------------------- PE table (b,e) -> 2048 floats
__global__ __launch_bounds__(256) void pe_tab_k(float* __restrict__ pet) {
    int i = blockIdx.x * 256 + threadIdx.x;          // 2048
    int e = i & (E_DIM - 1);
    float t = (float)(i >> 9) + 1.0f;
    int ee = (e & 1) ? (e + 1) : e;
    float w = exp2f((-(float)ee / 512.0f) * 13.287712379549449f);
    pet[i] = (e & 1) ? cosf(t * w) : sinf(t * w);
}

__global__ __launch_bounds__(256) void pe_add_k(const float* __restrict__ x,
                                                const float* __restrict__ pet,
                                                u16* __restrict__ xpb) {
    int idx = (blockIdx.x * 256 + threadIdx.x) * 4;
    f4v v = *(const f4v*)(x + idx);
    f4v p = *(const f4v*)(pet + (idx & 2047));
    u16x4 o;
#pragma unroll
    for (int i = 0; i < 4; ++i) o[i] = f2b(v[i] + p[i]);
    *(u16x4*)(xpb + idx) = o;
}

__global__ __launch_bounds__(256) void conv4_k(const float* __restrict__ s1, u16* __restrict__ d1, int n1,
                                               const float* __restrict__ s2, u16* __restrict__ d2, int n2,
                                               const float* __restrict__ s3, u16* __restrict__ d3, int n3,
                                               const float* __restrict__ s4, u16* __restrict__ d4) {
    int o = (blockIdx.x * 256 + threadIdx.x) * 4;
    const float* s; u16* d;
    if (o < n1) { s = s1; d = d1; }
    else { o -= n1;
        if (o < n2) { s = s2; d = d2; }
        else { o -= n2;
            if (o < n3) { s = s3; d = d3; }
            else { o -= n3; s = s4; d = d4; } } }
    f4v v = *(const f4v*)(s + o);
    u16x4 q;
#pragma unroll
    for (int i = 0; i < 4; ++i) q[i] = f2b(v[i]);
    *(u16x4*)(d + o) = q;
}

// ---------------------------------------------------------------- LN combine (wave per row)
template <int NP, bool WRITEF, bool WRITEB>
__global__ __launch_bounds__(256)
void ln_c(const u16* __restrict__ p0, const u16* __restrict__ p1,
          const u16* __restrict__ p2, const u16* __restrict__ p3,
          const float* __restrict__ bias, const u16* __restrict__ resid,
          const float* __restrict__ gw, const float* __restrict__ bw,
          float* __restrict__ outF, u16* __restrict__ outB) {
    int wave = threadIdx.x >> 6, lane = threadIdx.x & 63;
    size_t row = (size_t)blockIdx.x * 4 + wave;
    size_t off = row * E_DIM + lane * 8;
    u16x8 rv = *(const u16x8*)(resid + off);
    f4v a, b;
#pragma unroll
    for (int i = 0; i < 4; ++i) { a[i] = b2f(rv[i]); b[i] = b2f(rv[i + 4]); }
    a += *(const f4v*)(bias + lane * 8);
    b += *(const f4v*)(bias + lane * 8 + 4);
    const u16* ps[4] = {p0, p1, p2, p3};
#pragma unroll
    for (int z = 0; z < NP; ++z) {
        u16x8 t = *(const u16x8*)(ps[z] + off);
#pragma unroll
        for (int i = 0; i < 4; ++i) { a[i] += b2f(t[i]); b[i] += b2f(t[i + 4]); }
    }
    float s = (a[0] + a[1]) + (a[2] + a[3]) + (b[0] + b[1]) + (b[2] + b[3]);
#pragma unroll
    for (int o = 1; o < 64; o <<= 1) s += __shfl_xor(s, o, 64);
    float mu = s * (1.0f / E_DIM);
    float q = 0.f;
#pragma unroll
    for (int i = 0; i < 4; ++i) { float d = a[i] - mu; q += d * d; }
#pragma unroll
    for (int i = 0; i < 4; ++i) { float d = b[i] - mu; q += d * d; }
#pragma unroll
    for (int o = 1; o < 64; o <<= 1) q += __shfl_xor(q, o, 64);
    float rstd = rsqrtf(q * (1.0f / E_DIM) + 1e-5f);
    f4v g0 = *(const f4v*)(gw + lane * 8), g1 = *(const f4v*)(gw + lane * 8 + 4);
    f4v w0 = *(const f4v*)(bw + lane * 8), w1 = *(const f4v*)(bw + lane * 8 + 4);
    f4v y0, y1;
#pragma unroll
    for (int i = 0; i < 4; ++i) { y0[i] = (a[i] - mu) * rstd * g0[i] + w0[i];
                                  y1[i] = (b[i] - mu) * rstd * g1[i] + w1[i]; }
    if (WRITEF) {
        *(f4v*)(outF + off)     = y0;
        *(f4v*)(outF + off + 4) = y1;
    }
    if (WRITEB) {
        u16x8 o;
#pragma unroll
        for (int i = 0; i < 4; ++i) { o[i] = f2b(y0[i]); o[i + 4] = f2b(y1[i]); }
        *(u16x8*)(outB + off) = o;
    }
}

// ---------------------------------------------------------------- V transpose [b][h][l][d] -> [b][h][d][l]
__global__ __launch_bounds__(256) void transpose_v_k(const u16* __restrict__ vb,
                                                     u16* __restrict__ vt) {
    __shared__ __align__(16) u16 T[64 * 66];
    int t = threadIdx.x;
    int lt = blockIdx.x, bh = blockIdx.y;
    const u16* src = vb + (size_t)bh * (L_SEQ * HD) + (size_t)lt * 64 * HD;
    int lr = t >> 2, d0 = (t & 3) * 16;
    s8v va = *(const s8v*)(src + lr * HD + d0);
    s8v vb8 = *(const s8v*)(src + lr * HD + d0 + 8);
#pragma unroll
    for (int c = 0; c < 4; ++c) {
        u16x2 p0; p0[0] = (u16)va[c * 2]; p0[1] = (u16)va[c * 2 + 1];
        u16x2 p1; p1[0] = (u16)vb8[c * 2]; p1[1] = (u16)vb8[c * 2 + 1];
        *(u16x2*)(&T[lr * 66 + d0 + c * 2])     = p0;
        *(u16x2*)(&T[lr * 66 + d0 + 8 + c * 2]) = p1;
    }
    __syncthreads();
    int d = t >> 2, l0 = (t & 3) * 16;
    u16 tmp[16];
#pragma unroll
    for (int i = 0; i < 16; ++i) tmp[i] = T[(l0 + i) * 66 + d];
    u16* dst = vt + (size_t)bh * (L_SEQ * HD) + (size_t)d * L_SEQ + lt * 64 + l0;
    u16x8 o0, o1;
#pragma unroll
    for (int i = 0; i < 8; ++i) { o0[i] = tmp[i]; o1[i] = tmp[8 + i]; }
    *(u16x8*)dst       = o0;
    *(u16x8*)(dst + 8) = o1;
}

// ---------------------------------------------------------------- GEMM 128x128 BK32 dbuf + XCD swizzle (R14-proven)
// runtime K loop (compiler handles it better than full unroll — R15 lesson).
// NT = n-tiles. MODE 0: QKV scatter (Q pre-scaled); MODE 2: tanh-GELU bf16.
template <int MODE, int NT>
__global__ __launch_bounds__(256, 4)
void gemm_bt(const u16* __restrict__ A, const u16* __restrict__ Bw,
             const float* __restrict__ bias, int M, int N, int K,
             u16* __restrict__ outB,
             u16* __restrict__ oq, u16* __restrict__ okk, u16* __restrict__ ov) {
    __shared__ __align__(16) u16 As[2][128 * 32];
    __shared__ __align__(16) u16 Bs[2][128 * 32];
    const int tid = threadIdx.x;
    const int wave = tid >> 6, lane = tid & 63;
    const int col = lane & 15, quad = lane >> 4;
    const int n = blockIdx.x;
    const int xcd = n & 7, loc = n >> 3;
    const int mpx = (M / 128) >> 3;
    const int bm = (xcd * mpx + loc / NT) * 128;
    const int bn = (loc % NT) * 128;
    const int wm = (wave >> 1) * 64, wn = (wave & 1) * 64;
    f4v acc[4][4] = {};
    const int srow = wave * 16 + (lane >> 2);
    const int soff = (lane & 3) * 8;
    const u16* Ag = A + (size_t)(bm + srow) * K + soff;
    const u16* Bg = Bw + (size_t)(bn + srow) * K + soff;
    const int wo = wave * 512;
    gload_lds16(Ag,                  &As[0][wo]);
    gload_lds16(Ag + (size_t)64 * K, &As[0][wo + 2048]);
    gload_lds16(Bg,                  &Bs[0][wo]);
    gload_lds16(Bg + (size_t)64 * K, &Bs[0][wo + 2048]);
    const int nit = K >> 5;
    for (int t = 0; t < nit; ++t) {
        const int cur = t & 1, nxt = cur ^ 1;
        __syncthreads();
        if (t + 1 < nit) {
            const int kc = (t + 1) * 32;
            gload_lds16(Ag + kc,                  &As[nxt][wo]);
            gload_lds16(Ag + (size_t)64 * K + kc, &As[nxt][wo + 2048]);
            gload_lds16(Bg + kc,                  &Bs[nxt][wo]);
            gload_lds16(Bg + (size_t)64 * K + kc, &Bs[nxt][wo + 2048]);
        }
        s8v af[4], bf[4];
#pragma unroll
        for (int i = 0; i < 4; ++i) af[i] = *(const s8v*)(&As[cur][(wm + i * 16 + col) * 32 + quad * 8]);
#pragma unroll
        for (int j = 0; j < 4; ++j) bf[j] = *(const s8v*)(&Bs[cur][(wn + j * 16 + col) * 32 + quad * 8]);
#pragma unroll
        for (int i = 0; i < 4; ++i)
#pragma unroll
            for (int j = 0; j < 4; ++j)
                acc[i][j] = __builtin_amdgcn_mfma_f32_16x16x32_bf16(af[i], bf[j], acc[i][j], 0, 0, 0);
    }
#pragma unroll
    for (int j = 0; j < 4; ++j) {
        int gn = bn + wn + j * 16 + col;
        float bv = bias[gn];
        int which = gn >> 9, hh = (gn >> 6) & 7, d = gn & 63;
        u16* dst = (MODE == 0) ? ((which == 0) ? oq : ((which == 1) ? okk : ov)) : outB;
        float qs = (MODE == 0 && which == 0) ? QSCALE : 1.0f;
#pragma unroll
        for (int i = 0; i < 4; ++i) {
            int gm0 = bm + wm + i * 16 + quad * 4;
#pragma unroll
            for (int r = 0; r < 4; ++r) {
                float v = acc[i][j][r] + bv;
                int m = gm0 + r;
                if (MODE == 2) {
                    outB[(size_t)m * N + gn] = f2b(gelu_f(v));
                } else {
                    int l = m >> 2, bb = m & 3;
                    dst[((size_t)(bb * H_CNT + hh) * L_SEQ + l) * HD + d] = f2b(v * qs);
                }
            }
        }
    }
}

// ---------------------------------------------------------------- K-split partial GEMM BK32 dbuf + XCD swizzle (R14)
__global__ __launch_bounds__(256, 4)
void gemm_ks(const u16* __restrict__ A, const u16* __restrict__ Bw,
             int N, int K, int Kper,
             u16* __restrict__ q0, u16* __restrict__ q1) {
    __shared__ __align__(16) u16 As[2][128 * 32];
    __shared__ __align__(16) u16 Bs[2][128 * 32];
    const int tid = threadIdx.x;
    const int wave = tid >> 6, lane = tid & 63;
    const int col = lane & 15, quad = lane >> 4;
    const int n = blockIdx.x;
    const int xcd = n & 7, loc = n >> 3;             // loc in [0,64)
    const int bn = (loc & 3) * 128;
    const int bm = (xcd * 8 + ((loc >> 2) & 7)) * 128;
    const int kz = loc >> 5;
    u16* pz = kz ? q1 : q0;
    const int wm = (wave >> 1) * 64, wn = (wave & 1) * 64;
    f4v acc[4][4] = {};
    const int srow = wave * 16 + (lane >> 2);
    const int soff = (lane & 3) * 8;
    const u16* Ag = A + (size_t)(bm + srow) * K + kz * Kper + soff;
    const u16* Bg = Bw + (size_t)(bn + srow) * K + kz * Kper + soff;
    const int wo = wave * 512;
    gload_lds16(Ag,                  &As[0][wo]);
    gload_lds16(Ag + (size_t)64 * K, &As[0][wo + 2048]);
    gload_lds16(Bg,                  &Bs[0][wo]);
    gload_lds16(Bg + (size_t)64 * K, &Bs[0][wo + 2048]);
    const int nit = Kper >> 5;
    for (int t = 0; t < nit; ++t) {
        const int cur = t & 1, nxt = cur ^ 1;
        __syncthreads();
        if (t + 1 < nit) {
            const int kc = (t + 1) * 32;
            gload_lds16(Ag + kc,                  &As[nxt][wo]);
            gload_lds16(Ag + (size_t)64 * K + kc, &As[nxt][wo + 2048]);
            gload_lds16(Bg + kc,                  &Bs[nxt][wo]);
            gload_lds16(Bg + (size_t)64 * K + kc, &Bs[nxt][wo + 2048]);
        }
        s8v af[4], bf[4];
#pragma unroll
        for (int i = 0; i < 4; ++i) af[i] = *(const s8v*)(&As[cur][(wm + i * 16 + col) * 32 + quad * 8]);
#pragma unroll
        for (int j = 0; j < 4; ++j) bf[j] = *(const s8v*)(&Bs[cur][(wn + j * 16 + col) * 32 + quad * 8]);
#pragma unroll
        for (int i = 0; i < 4; ++i)
#pragma unroll
            for (int j = 0; j < 4; ++j)
                acc[i][j] = __builtin_amdgcn_mfma_f32_16x16x32_bf16(af[i], bf[j], acc[i][j], 0, 0, 0);
    }
#pragma unroll
    for (int j = 0; j < 4; ++j) {
        int gn = bn + wn + j * 16 + col;
#pragma unroll
        for (int i = 0; i < 4; ++i) {
            int m0 = bm + wm + i * 16 + quad * 4;
#pragma unroll
            for (int r = 0; r < 4; ++r)
                pz[(size_t)(m0 + r) * N + gn] = f2b(acc[i][j][r]);
        }
    }
}

// ---------------------------------------------------------------- flash attention v10: all-K32 MFMA, full-kv loop,
// in-register normalization. 2-wave blocks (64 q rows), grid 1024 = 32 qc x 32 bh, XCD-chunked
// (4 heads/XCD -> K/V L2-resident). 4 independent 2-wave barrier domains per CU for latency hiding.
// l-sum on VALU (off the MFMA pipe), verified in R3.
__global__ __launch_bounds__(128, 2)
void attn_k(const u16* __restrict__ qg, const u16* __restrict__ kg,
            const u16* __restrict__ vtg, u16* __restrict__ og) {
    __shared__ __align__(16) u16 Ks[2][2][64 * 32];
    __shared__ __align__(16) u16 Vs[2][2][64 * 32];
    const int tid = threadIdx.x;
    const int wave = tid >> 6, lane = tid & 63;
    const int col = lane & 15, quad = lane >> 4;
    const int flat = blockIdx.x;
    const int xcd = flat & 7, loc = flat >> 3;       // loc in [0,128)
    const int bh = xcd * 4 + (loc >> 5);             // 4 heads per XCD
    const int qc = loc & 31;                         // 32 q-chunks of 64 rows
    const size_t base = (size_t)bh * (L_SEQ * HD);
    s8v qf[2][2];
#pragma unroll
    for (int t = 0; t < 2; ++t) {
        const int qrow = qc * 64 + wave * 32 + t * 16 + col;
#pragma unroll
        for (int hh = 0; hh < 2; ++hh)
            qf[t][hh] = *(const s8v*)(qg + base + (size_t)qrow * HD + hh * 32 + quad * 8);
    }
    f4v oa[2][4] = {};
    float ls0 = 0.f, ls1 = 0.f;
    const int h = wave;                               // wave stages its whole h-half
    const int srow = lane >> 2, c = lane & 3;
    const int cp = c ^ ((srow >> 1) & 3);            // XOR-swizzled 16B chunk fetch
    // sigma row permutation: LDS row rho holds K-row 32*(rho>>5)+8*((rho>>2)&3)+4*((rho>>4)&1)+(rho&3)
    const u16* Kg[4];
    const u16* Vg[4];
#pragma unroll
    for (int z = 0; z < 4; ++z) {
        const int sig = 32 * (z >> 1) + 4 * (z & 1) + 8 * (srow >> 2) + (srow & 3);
        Kg[z] = kg + base + (size_t)sig * HD + h * 32 + cp * 8;
        Vg[z] = vtg + base + (size_t)(z * 16 + srow) * L_SEQ + h * 32 + cp * 8;
    }
    {
#pragma unroll
        for (int z = 0; z < 4; ++z) {
            gload_lds16(Kg[z], &Ks[0][h][(z * 16) * 32]);
            gload_lds16(Vg[z], &Vs[0][h][(z * 16) * 32]);
        }
    }
    const int perm = (col >> 1) & 3;
    for (int it = 0; it < 32; ++it) {
        const int cur = it & 1, nxt = cur ^ 1;
        __syncthreads();
        if (it + 1 < 32) {
            const int kv0 = (it + 1) * 64;
#pragma unroll
            for (int z = 0; z < 4; ++z) {
                gload_lds16(Kg[z] + (size_t)kv0 * HD, &Ks[nxt][h][(z * 16) * 32]);
                gload_lds16(Vg[z] + kv0,              &Vs[nxt][h][(z * 16) * 32]);
            }
        }
        f4v st[2][4];
#pragma unroll
        for (int j = 0; j < 4; ++j) {
            s8v k0 = *(const s8v*)(&Ks[cur][0][(j * 16 + col) * 32 + ((quad ^ perm) * 8)]);
            s8v k1 = *(const s8v*)(&Ks[cur][1][(j * 16 + col) * 32 + ((quad ^ perm) * 8)]);
#pragma unroll
            for (int t = 0; t < 2; ++t) {
                f4v z = {};
                z = __builtin_amdgcn_mfma_f32_16x16x32_bf16(k0, qf[t][0], z, 0, 0, 0);
                z = __builtin_amdgcn_mfma_f32_16x16x32_bf16(k1, qf[t][1], z, 0, 0, 0);
                st[t][j] = z;
            }
        }
        u32 pk[2][4][2];
#pragma unroll
        for (int t = 0; t < 2; ++t)
#pragma unroll
            for (int j = 0; j < 4; ++j) {
                f4v p;
#pragma unroll
                for (int r = 0; r < 4; ++r) p[r] = __builtin_amdgcn_exp2f(st[t][j][r]);
                float psum = (p[0] + p[1]) + (p[2] + p[3]);
                if (t == 0) ls0 += psum; else ls1 += psum;
                pk[t][j][0] = pk_trunc(p[0], p[1]);
                pk[t][j][1] = pk_trunc(p[2], p[3]);
            }
#pragma unroll
        for (int c2 = 0; c2 < 2; ++c2) {
            s8v pf[2];
#pragma unroll
            for (int t = 0; t < 2; ++t) {
                u32x4 q4 = {pk[t][2 * c2][0], pk[t][2 * c2][1],
                            pk[t][2 * c2 + 1][0], pk[t][2 * c2 + 1][1]};
                pf[t] = __builtin_bit_cast(s8v, q4);
            }
#pragma unroll
            for (int dj = 0; dj < 4; ++dj) {
                s8v vf = *(const s8v*)(&Vs[cur][c2][(dj * 16 + col) * 32 + ((quad ^ perm) * 8)]);
#pragma unroll
                for (int t = 0; t < 2; ++t)
                    oa[t][dj] = __builtin_amdgcn_mfma_f32_16x16x32_bf16(pf[t], vf, oa[t][dj], 0, 0, 0);
            }
        }
    }
    // complete l over quads (lanes sharing col), then normalize + write final O
    ls0 += __shfl_xor(ls0, 16, 64); ls0 += __shfl_xor(ls0, 32, 64);
    ls1 += __shfl_xor(ls1, 16, 64); ls1 += __shfl_xor(ls1, 32, 64);
    const int b = bh >> 3, hd = bh & 7;
#pragma unroll
    for (int t = 0; t < 2; ++t)
#pragma unroll
        for (int r = 0; r < 4; ++r) {
            float lv = __shfl(t == 0 ? ls0 : ls1, quad * 4 + r, 64);
            float inv = frcp(lv);
            int lrow = qc * 64 + wave * 32 + t * 16 + quad * 4 + r;
            size_t mrow = (size_t)(lrow * 4 + b) * E_DIM + hd * HD;
#pragma unroll
            for (int dj = 0; dj < 4; ++dj)
                og[mrow + dj * 16 + col] = f2b(oa[t][dj][r] * inv);
        }
}

// ---------------------------------------------------------------- host
extern "C" void kernel_launch(void* const* d_in, const int* in_sizes, int n_in,
                              void* d_out, int out_size, void* d_ws, size_t ws_size,
                              hipStream_t stream) {
    const float* x     = (const float*)d_in[0];
    const float* w_qkv = (const float*)d_in[1];
    const float* b_qkv = (const float*)d_in[2];
    const float* w_out = (const float*)d_in[3];
    const float* b_out = (const float*)d_in[4];
    const float* w1    = (const float*)d_in[5];
    const float* b1    = (const float*)d_in[6];
    const float* w2    = (const float*)d_in[7];
    const float* b2    = (const float*)d_in[8];
    const float* ln_g  = (const float*)d_in[9];
    const float* ln_b  = (const float*)d_in[10];

    char* ws = (char*)d_ws;
    u16*   WQKV = (u16*)(ws + 0);                    // 1.5 MB
    u16*   WOUT = (u16*)(ws + 1572864);              // 0.5 MB
    u16*   W1B  = (u16*)(ws + 2097152);              // 2 MB
    u16*   W2B  = (u16*)(ws + 4194304);              // 2 MB
    u16*   XPB  = (u16*)(ws + 6291456);              // 8 MB  x+pe bf16 (resid 1)
    u16*   QB   = (u16*)(ws + 14680064);             // 8 MB
    u16*   KB   = (u16*)(ws + 23068672);             // 8 MB
    u16*   VB   = (u16*)(ws + 31457280);             // 8 MB
    u16*   VT   = (u16*)(ws + 39845888);             // 8 MB
    float* PET  = (float*)(ws + 82837504);           // 8 KB PE table
    // aliases (disjoint lifetimes):
    u16*   OB   = VB;                                // attn out (VB free after transpose)
    u16*   OP0  = (u16*)(ws + 48234496);             // out-proj partials
    u16*   OP1  = (u16*)(ws + 56623104);
    u16*   X3B  = QB;                                // LN1 out bf16 (QB free after attn; resid 2)
    u16*   HB   = (u16*)(ws + 48234496);             // FFN1 out 32MB (over OPx, free after ln_c)
    u16*   FP0  = XPB;                               // FFN2 partials (free by FFN2)
    u16*   FP1  = KB;

    pe_tab_k<<<8, 256, 0, stream>>>(PET);
    pe_add_k<<<4096, 256, 0, stream>>>(x, PET, XPB);
    conv4_k<<<3072, 256, 0, stream>>>(w_qkv, WQKV, 3 * E_DIM * E_DIM,
                                      w_out, WOUT, E_DIM * E_DIM,
                                      w1, W1B, HID * E_DIM,
                                      w2, W2B);
    gemm_bt<0, 12><<<768, 256, 0, stream>>>(XPB, WQKV, b_qkv, M_ROWS, 3 * E_DIM, E_DIM,
                                            nullptr, QB, KB, VB);
    transpose_v_k<<<dim3(32, 32), 256, 0, stream>>>(VB, VT);
    attn_k<<<1024, 128, 0, stream>>>(QB, KB, VT, OB);
    gemm_ks<<<512, 256, 0, stream>>>(OB, WOUT, E_DIM, E_DIM, 256, OP0, OP1);
    ln_c<2, false, true><<<2048, 256, 0, stream>>>(OP0, OP1, nullptr, nullptr,
                                                   b_out, XPB, ln_g, ln_b, nullptr, X3B);
    gemm_bt<2, 16><<<1024, 256, 0, stream>>>(X3B, W1B, b1, M_ROWS, HID, E_DIM,
                                             HB, nullptr, nullptr, nullptr);
    gemm_ks<<<512, 256, 0, stream>>>(HB, W2B, E_DIM, HID, 1024, FP0, FP1);
    ln_c<2, true, false><<<2048, 256, 0, stream>>>(FP0, FP1, nullptr, nullptr,
                                                   b2, X3B, ln_g, ln_b, (float*)d_out, nullptr);
}

// Round 6
// 243.351 us; speedup vs baseline: 1.3387x; 1.0347x over previous
//
#include <hip/hip_runtime.h>

typedef unsigned short u16;
typedef unsigned int   u32;
typedef u16  u16x2 __attribute__((ext_vector_type(2)));
typedef u16  u16x4 __attribute__((ext_vector_type(4)));
typedef u16  u16x8 __attribute__((ext_vector_type(8)));
typedef short s8v  __attribute__((ext_vector_type(8)));   // 8 bf16, MFMA A/B frag (K=32 shapes)
typedef float f4v  __attribute__((ext_vector_type(4)));   // MFMA C/D frag
typedef u32  u32x2 __attribute__((ext_vector_type(2)));
typedef u32  u32x4 __attribute__((ext_vector_type(4)));

#define L_SEQ 2048
#define B_SZ  4
#define E_DIM 512
#define H_CNT 8
#define HD    64
#define HID   2048
#define M_ROWS (L_SEQ * B_SZ)   // 8192
#define QSCALE 0.18033688011112042f   // 0.125 * log2(e)

__device__ __forceinline__ u16 f2b(float f) {
    unsigned u = __builtin_bit_cast(unsigned, f);
    u += 0x7fffu + ((u >> 16) & 1u);               // RNE
    return (u16)(u >> 16);
}
__device__ __forceinline__ float b2f(u16 u) {
    u32 x = ((u32)u) << 16; return __builtin_bit_cast(float, x);
}
#if defined(__has_builtin)
#if __has_builtin(__builtin_amdgcn_cvt_pk_bf16_f32)
#define HAVE_PK_BF16 1
#endif
#if __has_builtin(__builtin_amdgcn_rcpf)
#define HAVE_RCPF 1
#endif
#endif
__device__ __forceinline__ u32 pk_trunc(float a, float b) {
#ifdef HAVE_PK_BF16
    typedef __bf16 bf2 __attribute__((ext_vector_type(2)));
    bf2 r = __builtin_amdgcn_cvt_pk_bf16_f32(a, b);
    return __builtin_bit_cast(u32, r);
#else
    u32 ua = __builtin_bit_cast(u32, a), ub = __builtin_bit_cast(u32, b);
    return (ua >> 16) | (ub & 0xffff0000u);
#endif
}
__device__ __forceinline__ float frcp(float x) {
#ifdef HAVE_RCPF
    return __builtin_amdgcn_rcpf(x);
#else
    return 1.0f / x;
#endif
}
__device__ __forceinline__ void gload_lds16(const u16* g, u16* l) {
    __builtin_amdgcn_global_load_lds((__attribute__((address_space(1))) void*)(u16*)g,
                                     (__attribute__((address_space(3))) void*)l, 16, 0, 0);
}
// tanh-GELU in sigmoid form (|err| < 1e-3, below bf16 rounding of the result)
__device__ __forceinline__ float gelu_f(float v) {
    float y2 = v * (1.5957691216f + 0.0713548576f * v * v);
    return v / (1.0f + __expf(-y2));
}

// ---------------------------------------------------------------- PE table (b,e) -> 2048 floats
__global__ __launch_bounds__(256) void pe_tab_k(float* __restrict__ pet) {
    int i = blockIdx.x * 256 + threadIdx.x;          // 2048
    int e = i & (E_DIM - 1);
    float t = (float)(i >> 9) + 1.0f;
    int ee = (e & 1) ? (e + 1) : e;
    float w = exp2f((-(float)ee / 512.0f) * 13.287712379549449f);
    pet[i] = (e & 1) ? cosf(t * w) : sinf(t * w);
}

__global__ __launch_bounds__(256) void pe_add_k(const float* __restrict__ x,
                                                const float* __restrict__ pet,
                                                u16* __restrict__ xpb) {
    int idx = (blockIdx.x * 256 + threadIdx.x) * 4;
    f4v v = *(const f4v*)(x + idx);
    f4v p = *(const f4v*)(pet + (idx & 2047));
    u16x4 o;
#pragma unroll
    for (int i = 0; i < 4; ++i) o[i] = f2b(v[i] + p[i]);
    *(u16x4*)(xpb + idx) = o;
}

__global__ __launch_bounds__(256) void conv4_k(const float* __restrict__ s1, u16* __restrict__ d1, int n1,
                                               const float* __restrict__ s2, u16* __restrict__ d2, int n2,
                                               const float* __restrict__ s3, u16* __restrict__ d3, int n3,
                                               const float* __restrict__ s4, u16* __restrict__ d4) {
    int o = (blockIdx.x * 256 + threadIdx.x) * 4;
    const float* s; u16* d;
    if (o < n1) { s = s1; d = d1; }
    else { o -= n1;
        if (o < n2) { s = s2; d = d2; }
        else { o -= n2;
            if (o < n3) { s = s3; d = d3; }
            else { o -= n3; s = s4; d = d4; } } }
    f4v v = *(const f4v*)(s + o);
    u16x4 q;
#pragma unroll
    for (int i = 0; i < 4; ++i) q[i] = f2b(v[i]);
    *(u16x4*)(d + o) = q;
}

// ---------------------------------------------------------------- LN combine (wave per row)
template <int NP, bool WRITEF, bool WRITEB>
__global__ __launch_bounds__(256)
void ln_c(const u16* __restrict__ p0, const u16* __restrict__ p1,
          const u16* __restrict__ p2, const u16* __restrict__ p3,
          const float* __restrict__ bias, const u16* __restrict__ resid,
          const float* __restrict__ gw, const float* __restrict__ bw,
          float* __restrict__ outF, u16* __restrict__ outB) {
    int wave = threadIdx.x >> 6, lane = threadIdx.x & 63;
    size_t row = (size_t)blockIdx.x * 4 + wave;
    size_t off = row * E_DIM + lane * 8;
    u16x8 rv = *(const u16x8*)(resid + off);
    f4v a, b;
#pragma unroll
    for (int i = 0; i < 4; ++i) { a[i] = b2f(rv[i]); b[i] = b2f(rv[i + 4]); }
    a += *(const f4v*)(bias + lane * 8);
    b += *(const f4v*)(bias + lane * 8 + 4);
    const u16* ps[4] = {p0, p1, p2, p3};
#pragma unroll
    for (int z = 0; z < NP; ++z) {
        u16x8 t = *(const u16x8*)(ps[z] + off);
#pragma unroll
        for (int i = 0; i < 4; ++i) { a[i] += b2f(t[i]); b[i] += b2f(t[i + 4]); }
    }
    float s = (a[0] + a[1]) + (a[2] + a[3]) + (b[0] + b[1]) + (b[2] + b[3]);
#pragma unroll
    for (int o = 1; o < 64; o <<= 1) s += __shfl_xor(s, o, 64);
    float mu = s * (1.0f / E_DIM);
    float q = 0.f;
#pragma unroll
    for (int i = 0; i < 4; ++i) { float d = a[i] - mu; q += d * d; }
#pragma unroll
    for (int i = 0; i < 4; ++i) { float d = b[i] - mu; q += d * d; }
#pragma unroll
    for (int o = 1; o < 64; o <<= 1) q += __shfl_xor(q, o, 64);
    float rstd = rsqrtf(q * (1.0f / E_DIM) + 1e-5f);
    f4v g0 = *(const f4v*)(gw + lane * 8), g1 = *(const f4v*)(gw + lane * 8 + 4);
    f4v w0 = *(const f4v*)(bw + lane * 8), w1 = *(const f4v*)(bw + lane * 8 + 4);
    f4v y0, y1;
#pragma unroll
    for (int i = 0; i < 4; ++i) { y0[i] = (a[i] - mu) * rstd * g0[i] + w0[i];
                                  y1[i] = (b[i] - mu) * rstd * g1[i] + w1[i]; }
    if (WRITEF) {
        *(f4v*)(outF + off)     = y0;
        *(f4v*)(outF + off + 4) = y1;
    }
    if (WRITEB) {
        u16x8 o;
#pragma unroll
        for (int i = 0; i < 4; ++i) { o[i] = f2b(y0[i]); o[i + 4] = f2b(y1[i]); }
        *(u16x8*)(outB + off) = o;
    }
}

// ---------------------------------------------------------------- V transpose [b][h][l][d] -> [b][h][d][l]
__global__ __launch_bounds__(256) void transpose_v_k(const u16* __restrict__ vb,
                                                     u16* __restrict__ vt) {
    __shared__ __align__(16) u16 T[64 * 66];
    int t = threadIdx.x;
    int lt = blockIdx.x, bh = blockIdx.y;
    const u16* src = vb + (size_t)bh * (L_SEQ * HD) + (size_t)lt * 64 * HD;
    int lr = t >> 2, d0 = (t & 3) * 16;
    s8v va = *(const s8v*)(src + lr * HD + d0);
    s8v vb8 = *(const s8v*)(src + lr * HD + d0 + 8);
#pragma unroll
    for (int c = 0; c < 4; ++c) {
        u16x2 p0; p0[0] = (u16)va[c * 2]; p0[1] = (u16)va[c * 2 + 1];
        u16x2 p1; p1[0] = (u16)vb8[c * 2]; p1[1] = (u16)vb8[c * 2 + 1];
        *(u16x2*)(&T[lr * 66 + d0 + c * 2])     = p0;
        *(u16x2*)(&T[lr * 66 + d0 + 8 + c * 2]) = p1;
    }
    __syncthreads();
    int d = t >> 2, l0 = (t & 3) * 16;
    u16 tmp[16];
#pragma unroll
    for (int i = 0; i < 16; ++i) tmp[i] = T[(l0 + i) * 66 + d];
    u16* dst = vt + (size_t)bh * (L_SEQ * HD) + (size_t)d * L_SEQ + lt * 64 + l0;
    u16x8 o0, o1;
#pragma unroll
    for (int i = 0; i < 8; ++i) { o0[i] = tmp[i]; o1[i] = tmp[8 + i]; }
    *(u16x8*)dst       = o0;
    *(u16x8*)(dst + 8) = o1;
}

// ---------------------------------------------------------------- GEMM 128x128 BK32 dbuf + XCD swizzle (R14-proven)
// runtime K loop (compiler handles it better than full unroll — R15 lesson).
// NT = n-tiles. MODE 0: QKV scatter (Q pre-scaled); MODE 2: tanh-GELU bf16.
template <int MODE, int NT>
__global__ __launch_bounds__(256, 4)
void gemm_bt(const u16* __restrict__ A, const u16* __restrict__ Bw,
             const float* __restrict__ bias, int M, int N, int K,
             u16* __restrict__ outB,
             u16* __restrict__ oq, u16* __restrict__ okk, u16* __restrict__ ov) {
    __shared__ __align__(16) u16 As[2][128 * 32];
    __shared__ __align__(16) u16 Bs[2][128 * 32];
    const int tid = threadIdx.x;
    const int wave = tid >> 6, lane = tid & 63;
    const int col = lane & 15, quad = lane >> 4;
    const int n = blockIdx.x;
    const int xcd = n & 7, loc = n >> 3;
    const int mpx = (M / 128) >> 3;
    const int bm = (xcd * mpx + loc / NT) * 128;
    const int bn = (loc % NT) * 128;
    const int wm = (wave >> 1) * 64, wn = (wave & 1) * 64;
    f4v acc[4][4] = {};
    const int srow = wave * 16 + (lane >> 2);
    const int soff = (lane & 3) * 8;
    const u16* Ag = A + (size_t)(bm + srow) * K + soff;
    const u16* Bg = Bw + (size_t)(bn + srow) * K + soff;
    const int wo = wave * 512;
    gload_lds16(Ag,                  &As[0][wo]);
    gload_lds16(Ag + (size_t)64 * K, &As[0][wo + 2048]);
    gload_lds16(Bg,                  &Bs[0][wo]);
    gload_lds16(Bg + (size_t)64 * K, &Bs[0][wo + 2048]);
    const int nit = K >> 5;
    for (int t = 0; t < nit; ++t) {
        const int cur = t & 1, nxt = cur ^ 1;
        __syncthreads();
        if (t + 1 < nit) {
            const int kc = (t + 1) * 32;
            gload_lds16(Ag + kc,                  &As[nxt][wo]);
            gload_lds16(Ag + (size_t)64 * K + kc, &As[nxt][wo + 2048]);
            gload_lds16(Bg + kc,                  &Bs[nxt][wo]);
            gload_lds16(Bg + (size_t)64 * K + kc, &Bs[nxt][wo + 2048]);
        }
        s8v af[4], bf[4];
#pragma unroll
        for (int i = 0; i < 4; ++i) af[i] = *(const s8v*)(&As[cur][(wm + i * 16 + col) * 32 + quad * 8]);
#pragma unroll
        for (int j = 0; j < 4; ++j) bf[j] = *(const s8v*)(&Bs[cur][(wn + j * 16 + col) * 32 + quad * 8]);
#pragma unroll
        for (int i = 0; i < 4; ++i)
#pragma unroll
            for (int j = 0; j < 4; ++j)
                acc[i][j] = __builtin_amdgcn_mfma_f32_16x16x32_bf16(af[i], bf[j], acc[i][j], 0, 0, 0);
    }
#pragma unroll
    for (int j = 0; j < 4; ++j) {
        int gn = bn + wn + j * 16 + col;
        float bv = bias[gn];
        int which = gn >> 9, hh = (gn >> 6) & 7, d = gn & 63;
        u16* dst = (MODE == 0) ? ((which == 0) ? oq : ((which == 1) ? okk : ov)) : outB;
        float qs = (MODE == 0 && which == 0) ? QSCALE : 1.0f;
#pragma unroll
        for (int i = 0; i < 4; ++i) {
            int gm0 = bm + wm + i * 16 + quad * 4;
#pragma unroll
            for (int r = 0; r < 4; ++r) {
                float v = acc[i][j][r] + bv;
                int m = gm0 + r;
                if (MODE == 2) {
                    outB[(size_t)m * N + gn] = f2b(gelu_f(v));
                } else {
                    int l = m >> 2, bb = m & 3;
                    dst[((size_t)(bb * H_CNT + hh) * L_SEQ + l) * HD + d] = f2b(v * qs);
                }
            }
        }
    }
}

// ---------------------------------------------------------------- K-split partial GEMM BK32 dbuf + XCD swizzle (R14)
__global__ __launch_bounds__(256, 4)
void gemm_ks(const u16* __restrict__ A, const u16* __restrict__ Bw,
             int N, int K, int Kper,
             u16* __restrict__ q0, u16* __restrict__ q1) {
    __shared__ __align__(16) u16 As[2][128 * 32];
    __shared__ __align__(16) u16 Bs[2][128 * 32];
    const int tid = threadIdx.x;
    const int wave = tid >> 6, lane = tid & 63;
    const int col = lane & 15, quad = lane >> 4;
    const int n = blockIdx.x;
    const int xcd = n & 7, loc = n >> 3;             // loc in [0,64)
    const int bn = (loc & 3) * 128;
    const int bm = (xcd * 8 + ((loc >> 2) & 7)) * 128;
    const int kz = loc >> 5;
    u16* pz = kz ? q1 : q0;
    const int wm = (wave >> 1) * 64, wn = (wave & 1) * 64;
    f4v acc[4][4] = {};
    const int srow = wave * 16 + (lane >> 2);
    const int soff = (lane & 3) * 8;
    const u16* Ag = A + (size_t)(bm + srow) * K + kz * Kper + soff;
    const u16* Bg = Bw + (size_t)(bn + srow) * K + kz * Kper + soff;
    const int wo = wave * 512;
    gload_lds16(Ag,                  &As[0][wo]);
    gload_lds16(Ag + (size_t)64 * K, &As[0][wo + 2048]);
    gload_lds16(Bg,                  &Bs[0][wo]);
    gload_lds16(Bg + (size_t)64 * K, &Bs[0][wo + 2048]);
    const int nit = Kper >> 5;
    for (int t = 0; t < nit; ++t) {
        const int cur = t & 1, nxt = cur ^ 1;
        __syncthreads();
        if (t + 1 < nit) {
            const int kc = (t + 1) * 32;
            gload_lds16(Ag + kc,                  &As[nxt][wo]);
            gload_lds16(Ag + (size_t)64 * K + kc, &As[nxt][wo + 2048]);
            gload_lds16(Bg + kc,                  &Bs[nxt][wo]);
            gload_lds16(Bg + (size_t)64 * K + kc, &Bs[nxt][wo + 2048]);
        }
        s8v af[4], bf[4];
#pragma unroll
        for (int i = 0; i < 4; ++i) af[i] = *(const s8v*)(&As[cur][(wm + i * 16 + col) * 32 + quad * 8]);
#pragma unroll
        for (int j = 0; j < 4; ++j) bf[j] = *(const s8v*)(&Bs[cur][(wn + j * 16 + col) * 32 + quad * 8]);
#pragma unroll
        for (int i = 0; i < 4; ++i)
#pragma unroll
            for (int j = 0; j < 4; ++j)
                acc[i][j] = __builtin_amdgcn_mfma_f32_16x16x32_bf16(af[i], bf[j], acc[i][j], 0, 0, 0);
    }
#pragma unroll
    for (int j = 0; j < 4; ++j) {
        int gn = bn + wn + j * 16 + col;
#pragma unroll
        for (int i = 0; i < 4; ++i) {
            int m0 = bm + wm + i * 16 + quad * 4;
#pragma unroll
            for (int r = 0; r < 4; ++r)
                pz[(size_t)(m0 + r) * N + gn] = f2b(acc[i][j][r]);
        }
    }
}

// ---------------------------------------------------------------- flash attention v12: v8 structure (proven 48.6us)
// + VALU l-sum (removes 4 of 36 MFMA/iter; verified on-HW in v9/v10). 4-wave blocks, 128 q rows,
// grid 512 = 16 qc x 32 bh XCD-chunked (K/V L2-resident). In-register normalization.
__global__ __launch_bounds__(256, 4)
void attn_k(const u16* __restrict__ qg, const u16* __restrict__ kg,
            const u16* __restrict__ vtg, u16* __restrict__ og) {
    __shared__ __align__(16) u16 Ks[2][2][64 * 32];
    __shared__ __align__(16) u16 Vs[2][2][64 * 32];
    const int tid = threadIdx.x;
    const int wave = tid >> 6, lane = tid & 63;
    const int col = lane & 15, quad = lane >> 4;
    const int flat = blockIdx.x;
    const int xcd = flat & 7, loc = flat >> 3;       // loc in [0,64)
    const int bh = xcd * 4 + (loc >> 4);             // 4 heads per XCD
    const int qc = loc & 15;
    const size_t base = (size_t)bh * (L_SEQ * HD);
    s8v qf[2][2];
#pragma unroll
    for (int t = 0; t < 2; ++t) {
        const int qrow = qc * 128 + wave * 32 + t * 16 + col;
#pragma unroll
        for (int hh = 0; hh < 2; ++hh)
            qf[t][hh] = *(const s8v*)(qg + base + (size_t)qrow * HD + hh * 32 + quad * 8);
    }
    f4v oa[2][4] = {};
    float ls0 = 0.f, ls1 = 0.f;
    const int h = wave & 1, r0 = (wave >> 1) * 16;
    const int srow = lane >> 2, c = lane & 3;
    const int cp = c ^ ((srow >> 1) & 3);            // XOR-swizzled 16B chunk fetch
    // sigma row permutation: LDS row rho holds K-row 32*(rho>>5)+8*((rho>>2)&3)+4*((rho>>4)&1)+(rho&3)
    const int sig = ((srow >> 2) << 3) + ((r0 >> 4) << 2) + (srow & 3);
    const u16* Kg = kg + base + (size_t)sig * HD + h * 32 + cp * 8;
    const u16* Vg = vtg + base + (size_t)(r0 + srow) * L_SEQ + h * 32 + cp * 8;
    {
        gload_lds16(Kg,                      &Ks[0][h][r0 * 32]);
        gload_lds16(Kg + (size_t)32 * HD,    &Ks[0][h][(r0 + 32) * 32]);
        gload_lds16(Vg,                      &Vs[0][h][r0 * 32]);
        gload_lds16(Vg + (size_t)32 * L_SEQ, &Vs[0][h][(r0 + 32) * 32]);
    }
    const int perm = (col >> 1) & 3;
    for (int it = 0; it < 32; ++it) {
        const int cur = it & 1, nxt = cur ^ 1;
        __syncthreads();
        if (it + 1 < 32) {
            const int kv0 = (it + 1) * 64;
            gload_lds16(Kg + (size_t)kv0 * HD,         &Ks[nxt][h][r0 * 32]);
            gload_lds16(Kg + (size_t)(kv0 + 32) * HD,  &Ks[nxt][h][(r0 + 32) * 32]);
            gload_lds16(Vg + kv0,                      &Vs[nxt][h][r0 * 32]);
            gload_lds16(Vg + kv0 + (size_t)32 * L_SEQ, &Vs[nxt][h][(r0 + 32) * 32]);
        }
        f4v st[2][4];
#pragma unroll
        for (int j = 0; j < 4; ++j) {
            s8v k0 = *(const s8v*)(&Ks[cur][0][(j * 16 + col) * 32 + ((quad ^ perm) * 8)]);
            s8v k1 = *(const s8v*)(&Ks[cur][1][(j * 16 + col) * 32 + ((quad ^ perm) * 8)]);
#pragma unroll
            for (int t = 0; t < 2; ++t) {
                f4v z = {};
                z = __builtin_amdgcn_mfma_f32_16x16x32_bf16(k0, qf[t][0], z, 0, 0, 0);
                z = __builtin_amdgcn_mfma_f32_16x16x32_bf16(k1, qf[t][1], z, 0, 0, 0);
                st[t][j] = z;
            }
        }
        u32 pk[2][4][2];
#pragma unroll
        for (int t = 0; t < 2; ++t)
#pragma unroll
            for (int j = 0; j < 4; ++j) {
                f4v p;
#pragma unroll
                for (int r = 0; r < 4; ++r) p[r] = __builtin_amdgcn_exp2f(st[t][j][r]);
                float psum = (p[0] + p[1]) + (p[2] + p[3]);
                if (t == 0) ls0 += psum; else ls1 += psum;
                pk[t][j][0] = pk_trunc(p[0], p[1]);
                pk[t][j][1] = pk_trunc(p[2], p[3]);
            }
#pragma unroll
        for (int c2 = 0; c2 < 2; ++c2) {
            s8v pf[2];
#pragma unroll
            for (int t = 0; t < 2; ++t) {
                u32x4 q4 = {pk[t][2 * c2][0], pk[t][2 * c2][1],
                            pk[t][2 * c2 + 1][0], pk[t][2 * c2 + 1][1]};
                pf[t] = __builtin_bit_cast(s8v, q4);
            }
#pragma unroll
            for (int dj = 0; dj < 4; ++dj) {
                s8v vf = *(const s8v*)(&Vs[cur][c2][(dj * 16 + col) * 32 + ((quad ^ perm) * 8)]);
#pragma unroll
                for (int t = 0; t < 2; ++t)
                    oa[t][dj] = __builtin_amdgcn_mfma_f32_16x16x32_bf16(pf[t], vf, oa[t][dj], 0, 0, 0);
            }
        }
    }
    // complete l over quads (lanes sharing col), then normalize + write final O
    ls0 += __shfl_xor(ls0, 16, 64); ls0 += __shfl_xor(ls0, 32, 64);
    ls1 += __shfl_xor(ls1, 16, 64); ls1 += __shfl_xor(ls1, 32, 64);
    const int b = bh >> 3, hd = bh & 7;
#pragma unroll
    for (int t = 0; t < 2; ++t)
#pragma unroll
        for (int r = 0; r < 4; ++r) {
            float lv = __shfl(t == 0 ? ls0 : ls1, quad * 4 + r, 64);
            float inv = frcp(lv);
            int lrow = qc * 128 + wave * 32 + t * 16 + quad * 4 + r;
            size_t mrow = (size_t)(lrow * 4 + b) * E_DIM + hd * HD;
#pragma unroll
            for (int dj = 0; dj < 4; ++dj)
                og[mrow + dj * 16 + col] = f2b(oa[t][dj][r] * inv);
        }
}

// ---------------------------------------------------------------- host
extern "C" void kernel_launch(void* const* d_in, const int* in_sizes, int n_in,
                              void* d_out, int out_size, void* d_ws, size_t ws_size,
                              hipStream_t stream) {
    const float* x     = (const float*)d_in[0];
    const float* w_qkv = (const float*)d_in[1];
    const float* b_qkv = (const float*)d_in[2];
    const float* w_out = (const float*)d_in[3];
    const float* b_out = (const float*)d_in[4];
    const float* w1    = (const float*)d_in[5];
    const float* b1    = (const float*)d_in[6];
    const float* w2    = (const float*)d_in[7];
    const float* b2    = (const float*)d_in[8];
    const float* ln_g  = (const float*)d_in[9];
    const float* ln_b  = (const float*)d_in[10];

    char* ws = (char*)d_ws;
    u16*   WQKV = (u16*)(ws + 0);                    // 1.5 MB
    u16*   WOUT = (u16*)(ws + 1572864);              // 0.5 MB
    u16*   W1B  = (u16*)(ws + 2097152);              // 2 MB
    u16*   W2B  = (u16*)(ws + 4194304);              // 2 MB
    u16*   XPB  = (u16*)(ws + 6291456);              // 8 MB  x+pe bf16 (resid 1)
    u16*   QB   = (u16*)(ws + 14680064);             // 8 MB
    u16*   KB   = (u16*)(ws + 23068672);             // 8 MB
    u16*   VB   = (u16*)(ws + 31457280);             // 8 MB
    u16*   VT   = (u16*)(ws + 39845888);             // 8 MB
    float* PET  = (float*)(ws + 82837504);           // 8 KB PE table
    // aliases (disjoint lifetimes):
    u16*   OB   = VB;                                // attn out (VB free after transpose)
    u16*   OP0  = (u16*)(ws + 48234496);             // out-proj partials
    u16*   OP1  = (u16*)(ws + 56623104);
    u16*   X3B  = QB;                                // LN1 out bf16 (QB free after attn; resid 2)
    u16*   HB   = (u16*)(ws + 48234496);             // FFN1 out 32MB (over OPx, free after ln_c)
    u16*   FP0  = XPB;                               // FFN2 partials (free by FFN2)
    u16*   FP1  = KB;

    pe_tab_k<<<8, 256, 0, stream>>>(PET);
    pe_add_k<<<4096, 256, 0, stream>>>(x, PET, XPB);
    conv4_k<<<3072, 256, 0, stream>>>(w_qkv, WQKV, 3 * E_DIM * E_DIM,
                                      w_out, WOUT, E_DIM * E_DIM,
                                      w1, W1B, HID * E_DIM,
                                      w2, W2B);
    gemm_bt<0, 12><<<768, 256, 0, stream>>>(XPB, WQKV, b_qkv, M_ROWS, 3 * E_DIM, E_DIM,
                                            nullptr, QB, KB, VB);
    transpose_v_k<<<dim3(32, 32), 256, 0, stream>>>(VB, VT);
    attn_k<<<512, 256, 0, stream>>>(QB, KB, VT, OB);
    gemm_ks<<<512, 256, 0, stream>>>(OB, WOUT, E_DIM, E_DIM, 256, OP0, OP1);
    ln_c<2, false, true><<<2048, 256, 0, stream>>>(OP0, OP1, nullptr, nullptr,
                                                   b_out, XPB, ln_g, ln_b, nullptr, X3B);
    gemm_bt<2, 16><<<1024, 256, 0, stream>>>(X3B, W1B, b1, M_ROWS, HID, E_DIM,
                                             HB, nullptr, nullptr, nullptr);
    gemm_ks<<<512, 256, 0, stream>>>(HB, W2B, E_DIM, HID, 1024, FP0, FP1);
    ln_c<2, true, false><<<2048, 256, 0, stream>>>(FP0, FP1, nullptr, nullptr,
                                                   b2, X3B, ln_g, ln_b, (float*)d_out, nullptr);
}